// Round 2
// baseline (146.669 us; speedup 1.0000x reference)
//
#include <hip/hip_runtime.h>
#include <math.h>

#define NG   512
#define NPER 256
#define DD   128
#define EPER 4096
#define KK   128

__global__ __launch_bounds__(256, 2) void sag_fused(
    const float* __restrict__ x,      // [N, 128] f32
    const int*   __restrict__ esrc,   // [E]
    const int*   __restrict__ edst,   // [E]
    const float* __restrict__ gcn_w,  // [128]
    const float* __restrict__ gcn_b,  // [1]
    const float* __restrict__ lin_w,  // [256, 128]
    const float* __restrict__ lin_b,  // [128]
    float* __restrict__ out)          // [512, 128]
{
  const int g    = blockIdx.x;
  const int tid  = threadIdx.x;
  const int lane = tid & 63;
  const int wave = tid >> 6;

  __shared__ float sW[DD];
  __shared__ float sXW[NPER];
  __shared__ float sScore[NPER];
  __shared__ float sDinv[NPER];
  __shared__ int   sDeg[NPER];
  __shared__ float sGate[NPER];
  __shared__ int   sKeep[NPER];
  __shared__ float sPartS[4][DD];
  __shared__ float sPartM[4][DD];
  __shared__ float sR[2 * DD];

  if (tid < DD) sW[tid] = gcn_w[tid];
  sDeg[tid] = 1;                       // self-loop
  __syncthreads();

  // ---- Phase 1: xw[i] = dot(x[i,:], w)  (8 lanes/node, 16 floats each)
  const float*  xg  = x + (size_t)g * NPER * DD;
  const float4* xg4 = (const float4*)xg;
  const int j  = lane & 7;             // position within 8-lane group: floats [j*16, j*16+16)
  const int gr = lane >> 3;            // group id within wave
  float wr[16];
  #pragma unroll
  for (int k = 0; k < 16; ++k) wr[k] = sW[j * 16 + k];

  #pragma unroll
  for (int i = 0; i < 8; ++i) {
    int node = wave * 64 + i * 8 + gr;
    const float4* p = xg4 + node * 32 + j * 4;
    float4 q0 = p[0], q1 = p[1], q2 = p[2], q3 = p[3];
    float acc = q0.x * wr[0]  + q0.y * wr[1]  + q0.z * wr[2]  + q0.w * wr[3]
              + q1.x * wr[4]  + q1.y * wr[5]  + q1.z * wr[6]  + q1.w * wr[7]
              + q2.x * wr[8]  + q2.y * wr[9]  + q2.z * wr[10] + q2.w * wr[11]
              + q3.x * wr[12] + q3.y * wr[13] + q3.z * wr[14] + q3.w * wr[15];
    acc += __shfl_xor(acc, 1);
    acc += __shfl_xor(acc, 2);
    acc += __shfl_xor(acc, 4);
    if (j == 0) sXW[node] = acc;
  }
  __syncthreads();

  // ---- Phase 2: in-degree (+self-loop), dinv, self-loop message
  const int* es = esrc + (size_t)g * EPER;
  const int* ed = edst + (size_t)g * EPER;
  for (int e = tid; e < EPER; e += 256) {
    atomicAdd(&sDeg[ed[e] & 255], 1);
  }
  __syncthreads();
  {
    float dv = 1.0f / sqrtf((float)sDeg[tid]);
    sDinv[tid]  = dv;
    sScore[tid] = sXW[tid] * dv * dv;  // self-loop term
  }
  __syncthreads();

  // ---- Phase 3: score[dst] += xw[src]*dinv[src]*dinv[dst]
  for (int e = tid; e < EPER; e += 256) {
    int s = es[e] & 255;
    int d = ed[e] & 255;
    atomicAdd(&sScore[d], sXW[s] * sDinv[s] * sDinv[d]);
  }
  __syncthreads();

  // ---- Phase 4: gate = tanh(score + b); stable top-K membership via rank count
  const float bval = gcn_b[0];
  {
    float s_i = sScore[tid];
    sGate[tid] = tanhf(s_i + bval);    // bias shifts all scores equally
    int rank = 0;
    for (int jj = 0; jj < NPER; ++jj) {
      float s_j = sScore[jj];          // LDS broadcast
      rank += (s_j > s_i) || (s_j == s_i && jj < tid);
    }
    sKeep[tid] = (rank < KK) ? 1 : 0;
  }
  __syncthreads();

  // ---- Phase 5: gated mean/max over kept nodes (wave w -> nodes [w*64, w*64+64))
  const float2* xg2 = (const float2*)xg;
  float sm0 = 0.f, sm1 = 0.f;
  float mx0 = -INFINITY, mx1 = -INFINITY;
  for (int n = 0; n < 64; ++n) {
    int node = wave * 64 + n;
    if (!sKeep[node]) continue;        // wave-uniform branch
    float gt = sGate[node];
    float2 p = xg2[node * 64 + lane];
    float a = p.x * gt;
    float b = p.y * gt;
    sm0 += a; sm1 += b;
    mx0 = fmaxf(mx0, a); mx1 = fmaxf(mx1, b);
  }
  sPartS[wave][lane * 2]     = sm0;
  sPartS[wave][lane * 2 + 1] = sm1;
  sPartM[wave][lane * 2]     = mx0;
  sPartM[wave][lane * 2 + 1] = mx1;
  __syncthreads();
  if (tid < DD) {
    float s = (sPartS[0][tid] + sPartS[1][tid]) + (sPartS[2][tid] + sPartS[3][tid]);
    float m = fmaxf(fmaxf(sPartM[0][tid], sPartM[1][tid]),
                    fmaxf(sPartM[2][tid], sPartM[3][tid]));
    sR[tid]      = s * (1.0f / KK);    // exact /128
    sR[DD + tid] = m;
  }
  __syncthreads();

  // ---- Phase 6: out[g,:] = [mean||max] @ lin_w + lin_b
  const float2* lw2 = (const float2*)lin_w;
  float a0 = 0.f, a1 = 0.f;
  #pragma unroll 4
  for (int kk = 0; kk < 64; ++kk) {
    int k = wave * 64 + kk;
    float rv = sR[k];                  // LDS broadcast
    float2 p = lw2[k * 64 + lane];
    a0 += rv * p.x;
    a1 += rv * p.y;
  }
  __syncthreads();                     // sPartS reuse guard
  sPartS[wave][lane * 2]     = a0;
  sPartS[wave][lane * 2 + 1] = a1;
  __syncthreads();
  if (tid < DD) {
    float o = (sPartS[0][tid] + sPartS[1][tid]) + (sPartS[2][tid] + sPartS[3][tid])
            + lin_b[tid];
    out[(size_t)g * DD + tid] = o;
  }
}

extern "C" void kernel_launch(void* const* d_in, const int* in_sizes, int n_in,
                              void* d_out, int out_size, void* d_ws, size_t ws_size,
                              hipStream_t stream) {
  const float* x  = (const float*)d_in[0];
  // d_in[1] = graph_indicator (unused: equal-size contiguous graphs)
  const int*   ei = (const int*)d_in[2];
  const float* gw = (const float*)d_in[3];
  const float* gb = (const float*)d_in[4];
  const float* lw = (const float*)d_in[5];
  const float* lb = (const float*)d_in[6];
  float* out = (float*)d_out;
  const int E = in_sizes[2] / 2;       // edge_index is [2, E]
  sag_fused<<<NG, 256, 0, stream>>>(x, ei, ei + E, gw, gb, lw, lb, out);
}

// Round 3
// 138.154 us; speedup vs baseline: 1.0616x; 1.0616x over previous
//
#include <hip/hip_runtime.h>
#include <math.h>

#define NG   512
#define NPER 256
#define DD   128
#define EPER 4096
#define KK   128
#define NT   1024
#define NW   16     // waves per block

__global__ __launch_bounds__(NT, 4) void sag_fused(
    const float* __restrict__ x,      // [N, 128] f32
    const int*   __restrict__ esrc,   // [E]
    const int*   __restrict__ edst,   // [E]
    const float* __restrict__ gcn_w,  // [128]
    const float* __restrict__ gcn_b,  // [1]
    const float* __restrict__ lin_w,  // [256, 128]
    const float* __restrict__ lin_b,  // [128]
    float* __restrict__ out)          // [512, 128]
{
  const int g    = blockIdx.x;
  const int tid  = threadIdx.x;
  const int lane = tid & 63;
  const int wave = tid >> 6;

  __shared__ float  sXW[NPER];
  __shared__ float  sScore[NPER];
  __shared__ float  sDinv[NPER];
  __shared__ int    sDeg[NPER];
  __shared__ int    sRank[NPER];
  __shared__ int    sKept[KK];
  __shared__ float  sGateK[KK];
  __shared__ float2 sPS[NW][64];      // sum partials (also reused for matvec)
  __shared__ float2 sPM[NW][64];      // max partials
  __shared__ float2 sR2[DD];          // readout: [0..63]=mean pairs, [64..127]=max pairs

  // ---- Edge prefetch: one int4 of src and one of dst per thread (4096 = 1024*4)
  const int4* es4 = (const int4*)(esrc + (size_t)g * EPER);
  const int4* ed4 = (const int4*)(edst + (size_t)g * EPER);
  int4 ev_s = es4[tid];
  int4 ev_d = ed4[tid];

  if (tid < NPER) { sDeg[tid] = 1; sRank[tid] = 0; }   // self-loop
  __syncthreads();

  // ---- Phase 1: xw[i] = dot(x[i,:], gcn_w); 32 lanes per node, float4/lane
  const float*  xg  = x + (size_t)g * NPER * DD;
  const float4* xg4 = (const float4*)xg;
  const int sl   = lane & 31;
  const int half = lane >> 5;
  float4 wr4 = ((const float4*)gcn_w)[sl];             // L2-broadcast
  #pragma unroll
  for (int r = 0; r < 8; ++r) {
    int node = r * 32 + wave * 2 + half;               // covers 0..255
    float4 q = xg4[node * 32 + sl];                    // coalesced 512B/half-wave
    float acc = q.x*wr4.x + q.y*wr4.y + q.z*wr4.z + q.w*wr4.w;
    acc += __shfl_xor(acc, 1);
    acc += __shfl_xor(acc, 2);
    acc += __shfl_xor(acc, 4);
    acc += __shfl_xor(acc, 8);
    acc += __shfl_xor(acc, 16);                        // reduce within 32-lane half
    if (sl == 0) sXW[node] = acc;
  }

  // ---- Phase 2: in-degree (edges already in regs; overlaps with Phase-1 loads)
  atomicAdd(&sDeg[ev_d.x & 255], 1);
  atomicAdd(&sDeg[ev_d.y & 255], 1);
  atomicAdd(&sDeg[ev_d.z & 255], 1);
  atomicAdd(&sDeg[ev_d.w & 255], 1);
  __syncthreads();

  if (tid < NPER) {
    float dv = 1.0f / sqrtf((float)sDeg[tid]);
    sDinv[tid]  = dv;
    sScore[tid] = sXW[tid] * dv * dv;                  // self-loop term
  }
  __syncthreads();

  // ---- Phase 3: score[dst] += xw[src]*dinv[src]*dinv[dst]
  {
    int s0 = ev_s.x & 255, d0 = ev_d.x & 255;
    int s1 = ev_s.y & 255, d1 = ev_d.y & 255;
    int s2 = ev_s.z & 255, d2 = ev_d.z & 255;
    int s3 = ev_s.w & 255, d3 = ev_d.w & 255;
    atomicAdd(&sScore[d0], sXW[s0] * sDinv[s0] * sDinv[d0]);
    atomicAdd(&sScore[d1], sXW[s1] * sDinv[s1] * sDinv[d1]);
    atomicAdd(&sScore[d2], sXW[s2] * sDinv[s2] * sDinv[d2]);
    atomicAdd(&sScore[d3], sXW[s3] * sDinv[s3] * sDinv[d3]);
  }
  __syncthreads();

  // ---- Phase 4: stable top-K rank (distributed 4-way: each thread counts 64 j's)
  {
    int node = tid & 255;
    int seg  = tid >> 8;                               // wave-uniform
    float s_i = sScore[node];
    int base = seg * 64;
    int part = 0;
    #pragma unroll 8
    for (int jj = base; jj < base + 64; ++jj) {
      float s_j = sScore[jj];                          // LDS broadcast
      part += (s_j > s_i) || (s_j == s_i && jj < node);
    }
    atomicAdd(&sRank[node], part);
  }
  __syncthreads();
  {
    const float bval = gcn_b[0];
    if (tid < NPER) {
      int r = sRank[tid];                              // ranks are a permutation
      if (r < KK) {
        sKept[r]  = tid;
        sGateK[r] = tanhf(sScore[tid] + bval);
      }
    }
  }
  __syncthreads();

  // ---- Phase 5: gated mean/max over kept nodes; wave w -> ranks [w*8, w*8+8)
  const float2* xg2 = (const float2*)xg;
  float sm0 = 0.f, sm1 = 0.f, mx0 = -INFINITY, mx1 = -INFINITY;
  #pragma unroll
  for (int t = 0; t < 8; ++t) {
    int kidx = wave * 8 + t;
    int node = sKept[kidx];                            // broadcast
    float gt = sGateK[kidx];                           // broadcast
    float2 p = xg2[node * 64 + lane];                  // coalesced (L3-hot)
    float a = p.x * gt, b = p.y * gt;
    sm0 += a; sm1 += b;
    mx0 = fmaxf(mx0, a); mx1 = fmaxf(mx1, b);
  }
  sPS[wave][lane] = make_float2(sm0, sm1);
  sPM[wave][lane] = make_float2(mx0, mx1);
  __syncthreads();

  // ---- combine: wave 0 -> mean, wave 1 -> max
  if (wave == 0) {
    float2 a = sPS[0][lane];
    #pragma unroll
    for (int w = 1; w < NW; ++w) { float2 p = sPS[w][lane]; a.x += p.x; a.y += p.y; }
    sR2[lane] = make_float2(a.x * (1.0f / KK), a.y * (1.0f / KK));
  } else if (wave == 1) {
    float2 a = sPM[0][lane];
    #pragma unroll
    for (int w = 1; w < NW; ++w) {
      float2 p = sPM[w][lane];
      a.x = fmaxf(a.x, p.x); a.y = fmaxf(a.y, p.y);
    }
    sR2[64 + lane] = a;
  }
  __syncthreads();

  // ---- Phase 6: out[g,:] = [mean||max] @ lin_w + lin_b; wave w -> k in [w*16,(w+1)*16)
  const float*  sR  = (const float*)sR2;
  const float2* lw2 = (const float2*)lin_w;
  float a0 = 0.f, a1 = 0.f;
  #pragma unroll
  for (int t = 0; t < 16; ++t) {
    int k = wave * 16 + t;
    float rv = sR[k];                                  // broadcast
    float2 p = lw2[k * 64 + lane];                     // L2-hot (shared by all blocks)
    a0 += rv * p.x;
    a1 += rv * p.y;
  }
  __syncthreads();                                     // sPS reuse guard
  sPS[wave][lane] = make_float2(a0, a1);
  __syncthreads();
  if (wave == 0) {
    float2 a = sPS[0][lane];
    #pragma unroll
    for (int w = 1; w < NW; ++w) { float2 p = sPS[w][lane]; a.x += p.x; a.y += p.y; }
    float2 bb = ((const float2*)lin_b)[lane];
    a.x += bb.x; a.y += bb.y;
    ((float2*)out)[(size_t)g * 64 + lane] = a;
  }
}

extern "C" void kernel_launch(void* const* d_in, const int* in_sizes, int n_in,
                              void* d_out, int out_size, void* d_ws, size_t ws_size,
                              hipStream_t stream) {
  const float* x  = (const float*)d_in[0];
  // d_in[1] = graph_indicator (unused: equal-size contiguous graphs)
  const int*   ei = (const int*)d_in[2];
  const float* gw = (const float*)d_in[3];
  const float* gb = (const float*)d_in[4];
  const float* lw = (const float*)d_in[5];
  const float* lb = (const float*)d_in[6];
  float* out = (float*)d_out;
  const int E = in_sizes[2] / 2;       // edge_index is [2, E]
  sag_fused<<<NG, NT, 0, stream>>>(x, ei, ei + E, gw, gb, lw, lb, out);
}

// Round 4
// 128.759 us; speedup vs baseline: 1.1391x; 1.0730x over previous
//
#include <hip/hip_runtime.h>
#include <math.h>

#define NG   512
#define NPER 256
#define DD   128
#define EPER 4096
#define KK   128
#define NT   512
#define NW   8      // waves per block

__global__ __launch_bounds__(NT, 4) void sag_fused(
    const float* __restrict__ x,      // [N, 128] f32
    const int*   __restrict__ esrc,   // [E]
    const int*   __restrict__ edst,   // [E]
    const float* __restrict__ gcn_w,  // [128]
    const float* __restrict__ gcn_b,  // [1]
    const float* __restrict__ lin_w,  // [256, 128]
    const float* __restrict__ lin_b,  // [128]
    float* __restrict__ out)          // [512, 128]
{
  const int g    = blockIdx.x;
  const int tid  = threadIdx.x;
  const int lane = tid & 63;
  const int wave = tid >> 6;

  __shared__ float  sXW[NPER];          // raw xw
  __shared__ float  sXWn[NPER];         // xw * dinv (pre-scaled)
  __shared__ float  sDinv[NPER];
  __shared__ int    sDeg[NPER];
  __shared__ int    sRank[NPER];
  __shared__ float4 sScore4[NPER / 4];  // scores, float4-addressable
  __shared__ int2   sKG[KK];            // packed (node, gate-bits) by rank
  __shared__ float2 sPS[NW][64];        // sum partials (reused for matvec)
  __shared__ float2 sPM[NW][64];        // max partials
  __shared__ float2 sR2[DD];            // readout pairs: [0..63]=mean, [64..127]=max
  float* sScore = (float*)sScore4;

  // ---- Edge prefetch: 8 edges/thread (4096 = 512*8), latency hides under Phase 1
  const int4* es4 = (const int4*)(esrc + (size_t)g * EPER);
  const int4* ed4 = (const int4*)(edst + (size_t)g * EPER);
  int4 sa = es4[tid], sb = es4[NT + tid];
  int4 da = ed4[tid], db = ed4[NT + tid];

  if (tid < NPER) { sDeg[tid] = 1; sRank[tid] = 0; }   // self-loop
  __syncthreads();                                      // B1

  // ---- Phase 1: xw[i] = dot(x[i,:], gcn_w). 16 lanes/node -> all shuffles are DPP.
  const float*  xg  = x + (size_t)g * NPER * DD;
  const float4* xg4 = (const float4*)xg;
  const int j   = lane & 15;            // position in 16-lane group
  const int sub = lane >> 4;            // group 0..3 within wave
  float4 wa = ((const float4*)gcn_w)[j];        // dims 4j..4j+3
  float4 wb = ((const float4*)gcn_w)[16 + j];   // dims 64+4j..
  #pragma unroll
  for (int r = 0; r < 8; ++r) {
    int node = r * 32 + wave * 4 + sub;         // 8*32=256 nodes
    float4 q0 = xg4[node * 32 + j];             // dims [4j, 4j+4)
    float4 q1 = xg4[node * 32 + 16 + j];        // dims [64+4j, ...)
    float acc = q0.x*wa.x + q0.y*wa.y + q0.z*wa.z + q0.w*wa.w
              + q1.x*wb.x + q1.y*wb.y + q1.z*wb.z + q1.w*wb.w;
    acc += __shfl_xor(acc, 1);                  // intra-row-16: DPP, VALU pipe
    acc += __shfl_xor(acc, 2);
    acc += __shfl_xor(acc, 4);
    acc += __shfl_xor(acc, 8);
    if (j == 0) sXW[node] = acc;
  }
  // ---- Phase 2: in-degree from registers (overlaps Phase-1 load latency)
  atomicAdd(&sDeg[da.x & 255], 1);
  atomicAdd(&sDeg[da.y & 255], 1);
  atomicAdd(&sDeg[da.z & 255], 1);
  atomicAdd(&sDeg[da.w & 255], 1);
  atomicAdd(&sDeg[db.x & 255], 1);
  atomicAdd(&sDeg[db.y & 255], 1);
  atomicAdd(&sDeg[db.z & 255], 1);
  atomicAdd(&sDeg[db.w & 255], 1);
  __syncthreads();                                      // B2

  if (tid < NPER) {
    float dv  = 1.0f / sqrtf((float)sDeg[tid]);
    float xwn = sXW[tid] * dv;
    sDinv[tid]  = dv;
    sXWn[tid]   = xwn;
    sScore[tid] = xwn * dv;             // self-loop term
  }
  __syncthreads();                                      // B3

  // ---- Phase 3: score[dst] += xwn[src] * dinv[dst]  (2 LDS reads + 1 atomic each)
  {
    int s0 = sa.x & 255, d0 = da.x & 255;
    int s1 = sa.y & 255, d1 = da.y & 255;
    int s2 = sa.z & 255, d2 = da.z & 255;
    int s3 = sa.w & 255, d3 = da.w & 255;
    int s4 = sb.x & 255, d4 = db.x & 255;
    int s5 = sb.y & 255, d5 = db.y & 255;
    int s6 = sb.z & 255, d6 = db.z & 255;
    int s7 = sb.w & 255, d7 = db.w & 255;
    atomicAdd(&sScore[d0], sXWn[s0] * sDinv[d0]);
    atomicAdd(&sScore[d1], sXWn[s1] * sDinv[d1]);
    atomicAdd(&sScore[d2], sXWn[s2] * sDinv[d2]);
    atomicAdd(&sScore[d3], sXWn[s3] * sDinv[d3]);
    atomicAdd(&sScore[d4], sXWn[s4] * sDinv[d4]);
    atomicAdd(&sScore[d5], sXWn[s5] * sDinv[d5]);
    atomicAdd(&sScore[d6], sXWn[s6] * sDinv[d6]);
    atomicAdd(&sScore[d7], sXWn[s7] * sDinv[d7]);
  }
  __syncthreads();                                      // B4

  // ---- Phase 4: stable top-K rank; 2 threads/node, float4 LDS reads
  {
    int node = tid & 255;
    int seg  = tid >> 8;                // 0 or 1: j in [seg*128, seg*128+128)
    float s_i = sScore[node];
    int base = seg * 32;                // float4 index
    int part = 0;
    #pragma unroll 8
    for (int t = 0; t < 32; ++t) {
      float4 v = sScore4[base + t];     // broadcast b128
      int jj = (base + t) * 4;
      part += (v.x > s_i) || (v.x == s_i && (jj + 0) < node);
      part += (v.y > s_i) || (v.y == s_i && (jj + 1) < node);
      part += (v.z > s_i) || (v.z == s_i && (jj + 2) < node);
      part += (v.w > s_i) || (v.w == s_i && (jj + 3) < node);
    }
    atomicAdd(&sRank[node], part);
  }
  __syncthreads();                                      // B5
  {
    const float bval = gcn_b[0];
    if (tid < NPER) {
      int r = sRank[tid];               // ranks are a permutation of 0..255
      if (r < KK) sKG[r] = make_int2(tid, __float_as_int(tanhf(sScore[tid] + bval)));
    }
  }
  __syncthreads();                                      // B6

  // ---- Phase 5: gated mean/max over kept; wave w -> ranks [w*16, w*16+16)
  const float2* xg2 = (const float2*)xg;
  float sm0 = 0.f, sm1 = 0.f, mx0 = -INFINITY, mx1 = -INFINITY;
  #pragma unroll
  for (int t = 0; t < 16; ++t) {
    int2 kg = sKG[wave * 16 + t];       // one b64 broadcast
    float gt = __int_as_float(kg.y);
    float2 p = xg2[kg.x * 64 + lane];   // coalesced, L3-hot
    float a = p.x * gt, b = p.y * gt;
    sm0 += a; sm1 += b;
    mx0 = fmaxf(mx0, a); mx1 = fmaxf(mx1, b);
  }
  sPS[wave][lane] = make_float2(sm0, sm1);
  sPM[wave][lane] = make_float2(mx0, mx1);
  __syncthreads();                                      // B7
  if (wave == 0) {
    float2 a = sPS[0][lane];
    #pragma unroll
    for (int w = 1; w < NW; ++w) { float2 p = sPS[w][lane]; a.x += p.x; a.y += p.y; }
    sR2[lane] = make_float2(a.x * (1.0f / KK), a.y * (1.0f / KK));
  } else if (wave == 1) {
    float2 a = sPM[0][lane];
    #pragma unroll
    for (int w = 1; w < NW; ++w) {
      float2 p = sPM[w][lane];
      a.x = fmaxf(a.x, p.x); a.y = fmaxf(a.y, p.y);
    }
    sR2[64 + lane] = a;
  }
  __syncthreads();                                      // B8

  // ---- Phase 6: out = [mean||max] @ lin_w + lin_b; wave w -> k in [w*32, w*32+32)
  const float2* lw2 = (const float2*)lin_w;
  float a0 = 0.f, a1 = 0.f;
  #pragma unroll
  for (int t = 0; t < 16; ++t) {
    int k2 = wave * 16 + t;             // float2 index over k
    float2 rv = sR2[k2];                // b64 broadcast = readout[2k2, 2k2+1]
    float2 p0 = lw2[(2 * k2) * 64 + lane];      // L2-hot
    float2 p1 = lw2[(2 * k2 + 1) * 64 + lane];
    a0 += rv.x * p0.x + rv.y * p1.x;
    a1 += rv.x * p0.y + rv.y * p1.y;
  }
  sPS[wave][lane] = make_float2(a0, a1);                // safe: all waves passed B8
  __syncthreads();                                      // B9
  if (wave == 0) {
    float2 a = sPS[0][lane];
    #pragma unroll
    for (int w = 1; w < NW; ++w) { float2 p = sPS[w][lane]; a.x += p.x; a.y += p.y; }
    float2 bb = ((const float2*)lin_b)[lane];
    a.x += bb.x; a.y += bb.y;
    ((float2*)out)[(size_t)g * 64 + lane] = a;
  }
}

extern "C" void kernel_launch(void* const* d_in, const int* in_sizes, int n_in,
                              void* d_out, int out_size, void* d_ws, size_t ws_size,
                              hipStream_t stream) {
  const float* x  = (const float*)d_in[0];
  // d_in[1] = graph_indicator (unused: equal-size contiguous graphs)
  const int*   ei = (const int*)d_in[2];
  const float* gw = (const float*)d_in[3];
  const float* gb = (const float*)d_in[4];
  const float* lw = (const float*)d_in[5];
  const float* lb = (const float*)d_in[6];
  float* out = (float*)d_out;
  const int E = in_sizes[2] / 2;       // edge_index is [2, E]
  sag_fused<<<NG, NT, 0, stream>>>(x, ei, ei + E, gw, gb, lw, lb, out);
}